// Round 3
// baseline (666.992 us; speedup 1.0000x reference)
//
#include <hip/hip_runtime.h>

#define F_EDGE 8
#define H 8

__device__ __forceinline__ unsigned short f2bf(float f) {
    unsigned u = __float_as_uint(f);
    unsigned r = u + 0x7fffu + ((u >> 16) & 1u);
    return (unsigned short)(r >> 16);
}
__device__ __forceinline__ float bflo(unsigned u) { return __uint_as_float(u << 16); }
__device__ __forceinline__ float bfhi(unsigned u) { return __uint_as_float(u & 0xffff0000u); }

// ---------------- dual CSR build (src-sorted AND dst-sorted) ----------------

__global__ __launch_bounds__(256) void zero_kernel(int* __restrict__ p, int n) {
    int i = blockIdx.x * 256 + threadIdx.x;
    if (i < n) p[i] = 0;
}

__global__ __launch_bounds__(256) void degree2_kernel(const int* __restrict__ ei,
                                                      int* __restrict__ degS,
                                                      int* __restrict__ degD, int E) {
    int e = blockIdx.x * 256 + threadIdx.x;
    if (e < E) {
        atomicAdd(&degS[ei[e]], 1);
        atomicAdd(&degD[ei[E + e]], 1);
    }
}

// Single-block exclusive scan for both degree arrays.
__global__ __launch_bounds__(1024) void scan2_kernel(
    const int* __restrict__ degS, int* __restrict__ offS, int* __restrict__ curS,
    const int* __restrict__ degD, int* __restrict__ offD, int* __restrict__ curD,
    int n) {
    __shared__ int s[1024];
    int t = threadIdx.x;
    int C = (n + 1023) >> 10;
#pragma unroll
    for (int pass = 0; pass < 2; ++pass) {
        const int* deg = pass ? degD : degS;
        int* off = pass ? offD : offS;
        int* cur = pass ? curD : curS;
        int base = t * C;
        int sum = 0;
        for (int i = 0; i < C; ++i) {
            int idx = base + i;
            if (idx < n) sum += deg[idx];
        }
        s[t] = sum;
        __syncthreads();
        for (int d = 1; d < 1024; d <<= 1) {
            int v = (t >= d) ? s[t - d] : 0;
            __syncthreads();
            s[t] += v;
            __syncthreads();
        }
        int run = (t == 0) ? 0 : s[t - 1];
        for (int i = 0; i < C; ++i) {
            int idx = base + i;
            if (idx < n) {
                off[idx] = run;
                cur[idx] = run;
                run += deg[idx];
            }
        }
        if (t == 1023) off[n] = s[1023];
        __syncthreads();
    }
}

// Scatter edges into both permutations, carrying a permuted copy of ea so the
// edge passes read ea fully coalesced (R1's fatal flaw was gathering ea).
__global__ __launch_bounds__(256) void scatter2_kernel(
    const int* __restrict__ ei, const float* __restrict__ ea,
    int* __restrict__ curS, int* __restrict__ curD,
    int* __restrict__ dsts_s, float* __restrict__ eas_s,
    int* __restrict__ srcs_d, float* __restrict__ eas_d, int E) {
    int e = blockIdx.x * 256 + threadIdx.x;
    if (e >= E) return;
    int s_ = ei[e];
    int d_ = ei[E + e];
    const float4* av = (const float4*)(ea + (long long)e * F_EDGE);
    float4 a0 = av[0], a1 = av[1];

    int pS = atomicAdd(&curS[s_], 1);
    dsts_s[pS] = d_;
    float4* o = (float4*)(eas_s + (long long)pS * F_EDGE);
    o[0] = a0; o[1] = a1;

    int pD = atomicAdd(&curD[d_], 1);
    srcs_d[pD] = s_;
    float4* o2 = (float4*)(eas_d + (long long)pD * F_EDGE);
    o2[0] = a0; o2[1] = a1;
}

// ---------------- Per-node precompute (unchanged) ---------------------------
//   Pt[n][j][k]   = sum_i feat[n][i] * We[k][i*H+j]   (stored bf16)
//   q[n][j]       = sum_i feat[n][i] * be[i*H+j]
//   aggseed[n][j] = b[j] + sum_i feat[n][i] * root[i*H+j]
template <int IN, bool RELU, bool INIT>
__global__ __launch_bounds__(256) void prep_kernel(
    const float* __restrict__ feat, const float* __restrict__ We,
    const float* __restrict__ be, const float* __restrict__ root,
    const float* __restrict__ b, unsigned short* __restrict__ Pt,
    float* __restrict__ q, float* __restrict__ aggseed, int n_nodes,
    float* __restrict__ out, const float* __restrict__ blast, int out_n) {
    __shared__ float sW[IN * H * 12];
    int tid = threadIdx.x;
    for (int t = tid; t < IN * H * 12; t += 256) {
        int r = t / 12, m = t - r * 12;   // r = i*H + j
        float v = 0.f;
        if (m < 8) v = We[m * (IN * H) + r];
        else if (m == 8) v = be[r];
        else if (m == 9) v = root[r];
        sW[t] = v;
    }
    if (INIT && blockIdx.x == 0) {
        float bl = blast[0];
        for (int t = tid; t < out_n; t += 256) out[t] = bl;
    }
    __syncthreads();

    int n = blockIdx.x * 32 + (tid >> 3);
    if (n >= n_nodes) return;
    int j = tid & 7;

    float f[IN];
    const float4* fv = (const float4*)(feat + (long long)n * IN);
#pragma unroll
    for (int i4 = 0; i4 < IN / 4; ++i4) {
        float4 v = fv[i4];
        f[i4 * 4 + 0] = v.x; f[i4 * 4 + 1] = v.y;
        f[i4 * 4 + 2] = v.z; f[i4 * 4 + 3] = v.w;
    }
    if (RELU) {
#pragma unroll
        for (int i = 0; i < IN; ++i) f[i] = f[i] > 0.f ? f[i] : 0.f;
    }

    float p[8] = {0.f, 0.f, 0.f, 0.f, 0.f, 0.f, 0.f, 0.f};
    float qq = 0.f, hr = 0.f;
#pragma unroll
    for (int i = 0; i < IN; ++i) {
        const float* row = &sW[(i * 8 + j) * 12];
        float4 w0 = *(const float4*)row;
        float4 w1 = *(const float4*)(row + 4);
        float2 br = *(const float2*)(row + 8);
        float fi = f[i];
        p[0] = fmaf(fi, w0.x, p[0]); p[1] = fmaf(fi, w0.y, p[1]);
        p[2] = fmaf(fi, w0.z, p[2]); p[3] = fmaf(fi, w0.w, p[3]);
        p[4] = fmaf(fi, w1.x, p[4]); p[5] = fmaf(fi, w1.y, p[5]);
        p[6] = fmaf(fi, w1.z, p[6]); p[7] = fmaf(fi, w1.w, p[7]);
        qq = fmaf(fi, br.x, qq);
        hr = fmaf(fi, br.y, hr);
    }
    uint4 pw;
    pw.x = (unsigned)f2bf(p[0]) | ((unsigned)f2bf(p[1]) << 16);
    pw.y = (unsigned)f2bf(p[2]) | ((unsigned)f2bf(p[3]) << 16);
    pw.z = (unsigned)f2bf(p[4]) | ((unsigned)f2bf(p[5]) << 16);
    pw.w = (unsigned)f2bf(p[6]) | ((unsigned)f2bf(p[7]) << 16);
    *(uint4*)(Pt + ((long long)n * H + j) * F_EDGE) = pw;
    q[(long long)n * H + j] = qq;
    aggseed[(long long)n * H + j] = hr + b[j];
}

// ---------------- Layer 1: src-CSR, atomics remain, NO gathers -------------
// One wave per SOURCE node: Pt[n]/q[n] live in registers (loaded once,
// coalesced); per out-edge: streamed dsts/eas, compute msg, atomicAdd to dst.
// Isolates the atomic cost (all reads coalesced).
__global__ __launch_bounds__(256) void edge_src_kernel(
    const int* __restrict__ offS, const int* __restrict__ dsts_s,
    const float* __restrict__ eas_s, const unsigned short* __restrict__ Pt,
    const float* __restrict__ q, float* __restrict__ agg, int n_nodes) {
    int n = blockIdx.x * 4 + (threadIdx.x >> 6);
    if (n >= n_nodes) return;
    int lane = threadIdx.x & 63;
    int es = lane >> 3, j = lane & 7;

    uint4 pw = *(const uint4*)(Pt + ((long long)n * H + j) * F_EDGE);
    float qj = q[(long long)n * H + j];

    int start = offS[n], end = offS[n + 1];
    for (int k = start + es; k < end; k += 8) {
        int dst = dsts_s[k];
        const float4* av = (const float4*)(eas_s + (long long)k * F_EDGE);
        float4 a0 = av[0], a1 = av[1];
        float m = qj;
        m = fmaf(a0.x, bflo(pw.x), m);
        m = fmaf(a0.y, bfhi(pw.x), m);
        m = fmaf(a0.z, bflo(pw.y), m);
        m = fmaf(a0.w, bfhi(pw.y), m);
        m = fmaf(a1.x, bflo(pw.z), m);
        m = fmaf(a1.y, bfhi(pw.z), m);
        m = fmaf(a1.z, bflo(pw.w), m);
        m = fmaf(a1.w, bfhi(pw.w), m);
        unsafeAtomicAdd(&agg[(long long)dst * H + j], m);
    }
}

// ---------------- Layer 2: dst-CSR, atomic-free, fused ReLU+Wlast pool -----
// One wave per DEST node: streamed srcs/eas, random Pt2/q2 gathers, wave
// reduce, per-node pooled contribution -> 1 atomic per node into out[batch].
// Isolates the gather cost (no edge atomics).
__global__ __launch_bounds__(256) void edge_dst_pool_kernel(
    const int* __restrict__ offD, const int* __restrict__ srcs_d,
    const float* __restrict__ eas_d, const unsigned short* __restrict__ Pt,
    const float* __restrict__ q, const float* __restrict__ seed,
    const int* __restrict__ batch, const float* __restrict__ Wlast,
    float* __restrict__ out, int n_nodes) {
    int n = blockIdx.x * 4 + (threadIdx.x >> 6);
    if (n >= n_nodes) return;
    int lane = threadIdx.x & 63;
    int es = lane >> 3, j = lane & 7;

    int start = offD[n], end = offD[n + 1];
    float acc = 0.f;
    for (int k = start + es; k < end; k += 8) {
        int src = srcs_d[k];
        const float4* av = (const float4*)(eas_d + (long long)k * F_EDGE);
        float4 a0 = av[0], a1 = av[1];
        uint4 pw = *(const uint4*)(Pt + ((long long)src * H + j) * F_EDGE);
        float m = q[(long long)src * H + j];
        m = fmaf(a0.x, bflo(pw.x), m);
        m = fmaf(a0.y, bfhi(pw.x), m);
        m = fmaf(a0.z, bflo(pw.y), m);
        m = fmaf(a0.w, bfhi(pw.y), m);
        m = fmaf(a1.x, bflo(pw.z), m);
        m = fmaf(a1.y, bfhi(pw.z), m);
        m = fmaf(a1.z, bflo(pw.w), m);
        m = fmaf(a1.w, bfhi(pw.w), m);
        acc += m;
    }
    acc += __shfl_xor(acc, 8);
    acc += __shfl_xor(acc, 16);
    acc += __shfl_xor(acc, 32);

    float h = seed[(long long)n * H + j] + acc;

    float c = fmaxf(h, 0.f) * Wlast[j];
    c += __shfl_xor(c, 1);
    c += __shfl_xor(c, 2);
    c += __shfl_xor(c, 4);
    if (lane == 0) unsafeAtomicAdd(&out[batch[n]], c);  // 1 atomic/node
}

extern "C" void kernel_launch(void* const* d_in, const int* in_sizes, int n_in,
                              void* d_out, int out_size, void* d_ws, size_t ws_size,
                              hipStream_t stream) {
    const float* x     = (const float*)d_in[0];
    const int*   ei    = (const int*)d_in[1];
    const float* ea    = (const float*)d_in[2];
    const int*   batch = (const int*)d_in[3];
    const float* We1   = (const float*)d_in[4];
    const float* be1   = (const float*)d_in[5];
    const float* root1 = (const float*)d_in[6];
    const float* b1    = (const float*)d_in[7];
    const float* We2   = (const float*)d_in[8];
    const float* be2   = (const float*)d_in[9];
    const float* root2 = (const float*)d_in[10];
    const float* b2    = (const float*)d_in[11];
    const float* Wlast = (const float*)d_in[12];
    const float* blast = (const float*)d_in[13];
    float* out = (float*)d_out;

    int F_IN_rt = 16;
    int n_nodes = in_sizes[0] / F_IN_rt;
    int E = in_sizes[1] / 2;

    char* w = (char*)d_ws;
    auto take = [&](size_t bytes) {
        char* p = w;
        w += (bytes + 15) & ~(size_t)15;
        return p;
    };
    unsigned short* Pt1 = (unsigned short*)take((size_t)n_nodes * H * F_EDGE * 2);
    unsigned short* Pt2 = (unsigned short*)take((size_t)n_nodes * H * F_EDGE * 2);
    float* q1    = (float*)take((size_t)n_nodes * H * 4);
    float* q2    = (float*)take((size_t)n_nodes * H * 4);
    float* h1    = (float*)take((size_t)n_nodes * H * 4);   // seed1, then h1 in place
    float* h2s   = (float*)take((size_t)n_nodes * H * 4);   // seed2
    int* degS    = (int*)take((size_t)n_nodes * 4);
    int* degD    = (int*)take((size_t)n_nodes * 4);
    int* offS    = (int*)take((size_t)(n_nodes + 1) * 4);
    int* offD    = (int*)take((size_t)(n_nodes + 1) * 4);
    int* curS    = (int*)take((size_t)n_nodes * 4);
    int* curD    = (int*)take((size_t)n_nodes * 4);
    int* dsts_s  = (int*)take((size_t)E * 4);
    int* srcs_d  = (int*)take((size_t)E * 4);
    float* eas_s = (float*)take((size_t)E * F_EDGE * 4);
    float* eas_d = (float*)take((size_t)E * F_EDGE * 4);

    int nbn2 = (2 * n_nodes + 255) / 256;
    int nbe = (E + 255) / 256;

    // dual CSR build (degS/degD are contiguous -> one zero kernel)
    zero_kernel<<<nbn2, 256, 0, stream>>>(degS, 2 * n_nodes);
    degree2_kernel<<<nbe, 256, 0, stream>>>(ei, degS, degD, E);
    scan2_kernel<<<1, 1024, 0, stream>>>(degS, offS, curS, degD, offD, curD, n_nodes);
    scatter2_kernel<<<nbe, 256, 0, stream>>>(ei, ea, curS, curD,
                                             dsts_s, eas_s, srcs_d, eas_d, E);

    int nblocks = (n_nodes + 31) / 32;
    prep_kernel<16, false, true><<<nblocks, 256, 0, stream>>>(
        x, We1, be1, root1, b1, Pt1, q1, h1, n_nodes, out, blast, out_size);

    int ablk = (n_nodes + 3) / 4;
    // layer 1: src-CSR + atomics (all reads coalesced / register-resident)
    edge_src_kernel<<<ablk, 256, 0, stream>>>(offS, dsts_s, eas_s, Pt1, q1, h1, n_nodes);

    prep_kernel<H, true, false><<<nblocks, 256, 0, stream>>>(
        h1, We2, be2, root2, b2, Pt2, q2, h2s, n_nodes, nullptr, nullptr, 0);

    // layer 2: dst-CSR, atomic-free, fused pool (pool_kernel eliminated)
    edge_dst_pool_kernel<<<ablk, 256, 0, stream>>>(
        offD, srcs_d, eas_d, Pt2, q2, h2s, batch, Wlast, out, n_nodes);
}

// Round 4
// 357.889 us; speedup vs baseline: 1.8637x; 1.8637x over previous
//
#include <hip/hip_runtime.h>

#define F_EDGE 8
#define H 8

__device__ __forceinline__ unsigned short f2bf(float f) {
    unsigned u = __float_as_uint(f);
    unsigned r = u + 0x7fffu + ((u >> 16) & 1u);
    return (unsigned short)(r >> 16);
}
__device__ __forceinline__ float bflo(unsigned u) { return __uint_as_float(u << 16); }
__device__ __forceinline__ float bfhi(unsigned u) { return __uint_as_float(u & 0xffff0000u); }

// ---------------- dst-CSR build (no scan kernel!) ---------------------------

// zeros deg[0..n_nodes] where slot n_nodes doubles as the global total counter
__global__ __launch_bounds__(256) void zero_kernel(int* __restrict__ p, int n) {
    int i = blockIdx.x * 256 + threadIdx.x;
    if (i < n) p[i] = 0;
}

__global__ __launch_bounds__(256) void degree_kernel(const int* __restrict__ ei,
                                                     int* __restrict__ deg, int E) {
    int e = blockIdx.x * 256 + threadIdx.x;
    if (e < E) atomicAdd(&deg[ei[E + e]], 1);
}

// Wave-parallel segment reservation: 64-lane inclusive shfl-scan of degrees,
// ONE atomicAdd per wave on the global counter. Segment order is arbitrary,
// which is fine: consumers use off[n] + deg[n], never off[n+1].
__global__ __launch_bounds__(256) void reserve_kernel(
    const int* __restrict__ deg, int* __restrict__ off, int* __restrict__ cur,
    int* __restrict__ total, int n) {
    int i = blockIdx.x * 256 + threadIdx.x;
    int lane = threadIdx.x & 63;
    int d = (i < n) ? deg[i] : 0;
    int s = d;
#pragma unroll
    for (int k = 1; k < 64; k <<= 1) {
        int v = __shfl_up(s, k);
        if (lane >= k) s += v;
    }
    int wavetotal = __shfl(s, 63);
    int base = 0;
    if (lane == 63) base = atomicAdd(total, wavetotal);
    base = __shfl(base, 63);
    if (i < n) {
        int o = base + (s - d);
        off[i] = o;
        cur[i] = o;
    }
}

// Scatter edges into dst-grouped order, carrying a permuted copy of ea so the
// two edge passes read ea fully streamed (R1 showed gathered ea is fatal).
__global__ __launch_bounds__(256) void scatter_kernel(
    const int* __restrict__ ei, const float* __restrict__ ea,
    int* __restrict__ cur, int* __restrict__ srcs, float* __restrict__ eas,
    int E) {
    int e = blockIdx.x * 256 + threadIdx.x;
    if (e >= E) return;
    int s_ = ei[e];
    int d_ = ei[E + e];
    const float4* av = (const float4*)(ea + (long long)e * F_EDGE);
    float4 a0 = av[0], a1 = av[1];
    int p = atomicAdd(&cur[d_], 1);
    srcs[p] = s_;
    float4* o = (float4*)(eas + (long long)p * F_EDGE);
    o[0] = a0; o[1] = a1;
}

// ---------------- Per-node precompute (unchanged) ---------------------------
//   Pt[n][j][k]   = sum_i feat[n][i] * We[k][i*H+j]   (stored bf16)
//   q[n][j]       = sum_i feat[n][i] * be[i*H+j]
//   aggseed[n][j] = b[j] + sum_i feat[n][i] * root[i*H+j]
template <int IN, bool RELU, bool INIT>
__global__ __launch_bounds__(256) void prep_kernel(
    const float* __restrict__ feat, const float* __restrict__ We,
    const float* __restrict__ be, const float* __restrict__ root,
    const float* __restrict__ b, unsigned short* __restrict__ Pt,
    float* __restrict__ q, float* __restrict__ aggseed, int n_nodes,
    float* __restrict__ out, const float* __restrict__ blast, int out_n) {
    __shared__ float sW[IN * H * 12];
    int tid = threadIdx.x;
    for (int t = tid; t < IN * H * 12; t += 256) {
        int r = t / 12, m = t - r * 12;   // r = i*H + j
        float v = 0.f;
        if (m < 8) v = We[m * (IN * H) + r];
        else if (m == 8) v = be[r];
        else if (m == 9) v = root[r];
        sW[t] = v;
    }
    if (INIT && blockIdx.x == 0) {
        float bl = blast[0];
        for (int t = tid; t < out_n; t += 256) out[t] = bl;
    }
    __syncthreads();

    int n = blockIdx.x * 32 + (tid >> 3);
    if (n >= n_nodes) return;
    int j = tid & 7;

    float f[IN];
    const float4* fv = (const float4*)(feat + (long long)n * IN);
#pragma unroll
    for (int i4 = 0; i4 < IN / 4; ++i4) {
        float4 v = fv[i4];
        f[i4 * 4 + 0] = v.x; f[i4 * 4 + 1] = v.y;
        f[i4 * 4 + 2] = v.z; f[i4 * 4 + 3] = v.w;
    }
    if (RELU) {
#pragma unroll
        for (int i = 0; i < IN; ++i) f[i] = f[i] > 0.f ? f[i] : 0.f;
    }

    float p[8] = {0.f, 0.f, 0.f, 0.f, 0.f, 0.f, 0.f, 0.f};
    float qq = 0.f, hr = 0.f;
#pragma unroll
    for (int i = 0; i < IN; ++i) {
        const float* row = &sW[(i * 8 + j) * 12];
        float4 w0 = *(const float4*)row;
        float4 w1 = *(const float4*)(row + 4);
        float2 br = *(const float2*)(row + 8);
        float fi = f[i];
        p[0] = fmaf(fi, w0.x, p[0]); p[1] = fmaf(fi, w0.y, p[1]);
        p[2] = fmaf(fi, w0.z, p[2]); p[3] = fmaf(fi, w0.w, p[3]);
        p[4] = fmaf(fi, w1.x, p[4]); p[5] = fmaf(fi, w1.y, p[5]);
        p[6] = fmaf(fi, w1.z, p[6]); p[7] = fmaf(fi, w1.w, p[7]);
        qq = fmaf(fi, br.x, qq);
        hr = fmaf(fi, br.y, hr);
    }
    uint4 pw;
    pw.x = (unsigned)f2bf(p[0]) | ((unsigned)f2bf(p[1]) << 16);
    pw.y = (unsigned)f2bf(p[2]) | ((unsigned)f2bf(p[3]) << 16);
    pw.z = (unsigned)f2bf(p[4]) | ((unsigned)f2bf(p[5]) << 16);
    pw.w = (unsigned)f2bf(p[6]) | ((unsigned)f2bf(p[7]) << 16);
    *(uint4*)(Pt + ((long long)n * H + j) * F_EDGE) = pw;
    q[(long long)n * H + j] = qq;
    aggseed[(long long)n * H + j] = hr + b[j];
}

// ---------------- dst-CSR aggregation: atomic-free --------------------------
// One wave per DEST node. lane = es*8 + j. Streamed srcs/eas; Pt/q gathers
// (128B + 32B contiguous per edge, L2-cacheable). shfl reduce over es.
// Layer 1: one coalesced 32B store per node.
// Layer 2: fused ReLU -> Wlast dot -> 1 atomic per node into out[batch[n]].
template <bool FUSE_POOL>
__global__ __launch_bounds__(256) void edge_agg_kernel(
    const int* __restrict__ off, const int* __restrict__ deg,
    const int* __restrict__ srcs, const float* __restrict__ eas,
    const unsigned short* __restrict__ Pt, const float* __restrict__ q,
    const float* __restrict__ seed, float* __restrict__ hout,
    const int* __restrict__ batch, const float* __restrict__ Wlast,
    float* __restrict__ out, int n_nodes) {
    int n = blockIdx.x * 4 + (threadIdx.x >> 6);
    if (n >= n_nodes) return;
    int lane = threadIdx.x & 63;
    int es = lane >> 3, j = lane & 7;

    int start = off[n];
    int end = start + deg[n];
    float acc = 0.f;
    for (int k = start + es; k < end; k += 8) {
        int src = srcs[k];
        const float4* av = (const float4*)(eas + (long long)k * F_EDGE);
        float4 a0 = av[0], a1 = av[1];
        uint4 pw = *(const uint4*)(Pt + ((long long)src * H + j) * F_EDGE);
        float m = q[(long long)src * H + j];
        m = fmaf(a0.x, bflo(pw.x), m);
        m = fmaf(a0.y, bfhi(pw.x), m);
        m = fmaf(a0.z, bflo(pw.y), m);
        m = fmaf(a0.w, bfhi(pw.y), m);
        m = fmaf(a1.x, bflo(pw.z), m);
        m = fmaf(a1.y, bfhi(pw.z), m);
        m = fmaf(a1.z, bflo(pw.w), m);
        m = fmaf(a1.w, bfhi(pw.w), m);
        acc += m;
    }
    acc += __shfl_xor(acc, 8);
    acc += __shfl_xor(acc, 16);
    acc += __shfl_xor(acc, 32);

    float h = seed[(long long)n * H + j] + acc;

    if (!FUSE_POOL) {
        if (es == 0) hout[(long long)n * H + j] = h;   // coalesced 32B/node
    } else {
        float c = fmaxf(h, 0.f) * Wlast[j];
        c += __shfl_xor(c, 1);
        c += __shfl_xor(c, 2);
        c += __shfl_xor(c, 4);
        if (lane == 0) unsafeAtomicAdd(&out[batch[n]], c);  // 1 atomic/node
    }
}

extern "C" void kernel_launch(void* const* d_in, const int* in_sizes, int n_in,
                              void* d_out, int out_size, void* d_ws, size_t ws_size,
                              hipStream_t stream) {
    const float* x     = (const float*)d_in[0];
    const int*   ei    = (const int*)d_in[1];
    const float* ea    = (const float*)d_in[2];
    const int*   batch = (const int*)d_in[3];
    const float* We1   = (const float*)d_in[4];
    const float* be1   = (const float*)d_in[5];
    const float* root1 = (const float*)d_in[6];
    const float* b1    = (const float*)d_in[7];
    const float* We2   = (const float*)d_in[8];
    const float* be2   = (const float*)d_in[9];
    const float* root2 = (const float*)d_in[10];
    const float* b2    = (const float*)d_in[11];
    const float* Wlast = (const float*)d_in[12];
    const float* blast = (const float*)d_in[13];
    float* out = (float*)d_out;

    int F_IN_rt = 16;
    int n_nodes = in_sizes[0] / F_IN_rt;
    int E = in_sizes[1] / 2;

    char* w = (char*)d_ws;
    auto take = [&](size_t bytes) {
        char* p = w;
        w += (bytes + 15) & ~(size_t)15;
        return p;
    };
    unsigned short* Pt1 = (unsigned short*)take((size_t)n_nodes * H * F_EDGE * 2);
    unsigned short* Pt2 = (unsigned short*)take((size_t)n_nodes * H * F_EDGE * 2);
    float* q1    = (float*)take((size_t)n_nodes * H * 4);
    float* q2    = (float*)take((size_t)n_nodes * H * 4);
    float* h1    = (float*)take((size_t)n_nodes * H * 4);   // seed1, then h1 in place
    float* h2s   = (float*)take((size_t)n_nodes * H * 4);   // seed2
    int* deg     = (int*)take((size_t)(n_nodes + 1) * 4);   // deg[n_nodes] = total ctr
    int* off     = (int*)take((size_t)n_nodes * 4);
    int* cur     = (int*)take((size_t)n_nodes * 4);
    int* srcs    = (int*)take((size_t)E * 4);
    float* eas   = (float*)take((size_t)E * F_EDGE * 4);

    int* total = deg + n_nodes;

    int nbz = (n_nodes + 1 + 255) / 256;
    int nbn = (n_nodes + 255) / 256;
    int nbe = (E + 255) / 256;

    // dst-CSR build (scan-free)
    zero_kernel<<<nbz, 256, 0, stream>>>(deg, n_nodes + 1);
    degree_kernel<<<nbe, 256, 0, stream>>>(ei, deg, E);
    reserve_kernel<<<nbn, 256, 0, stream>>>(deg, off, cur, total, n_nodes);
    scatter_kernel<<<nbe, 256, 0, stream>>>(ei, ea, cur, srcs, eas, E);

    int nblocks = (n_nodes + 31) / 32;
    prep_kernel<16, false, true><<<nblocks, 256, 0, stream>>>(
        x, We1, be1, root1, b1, Pt1, q1, h1, n_nodes, out, blast, out_size);

    int ablk = (n_nodes + 3) / 4;
    edge_agg_kernel<false><<<ablk, 256, 0, stream>>>(
        off, deg, srcs, eas, Pt1, q1, h1, h1, nullptr, nullptr, nullptr, n_nodes);

    prep_kernel<H, true, false><<<nblocks, 256, 0, stream>>>(
        h1, We2, be2, root2, b2, Pt2, q2, h2s, n_nodes, nullptr, nullptr, 0);

    edge_agg_kernel<true><<<ablk, 256, 0, stream>>>(
        off, deg, srcs, eas, Pt2, q2, h2s, nullptr, batch, Wlast, out, n_nodes);
}

// Round 5
// 255.621 us; speedup vs baseline: 2.6093x; 1.4001x over previous
//
#include <hip/hip_runtime.h>

#define F_EDGE 8
#define H 8

__device__ __forceinline__ unsigned short f2bf(float f) {
    unsigned u = __float_as_uint(f);
    unsigned r = u + 0x7fffu + ((u >> 16) & 1u);
    return (unsigned short)(r >> 16);
}
__device__ __forceinline__ float bflo(unsigned u) { return __uint_as_float(u << 16); }
__device__ __forceinline__ float bfhi(unsigned u) { return __uint_as_float(u & 0xffff0000u); }

// ---------------- dst-grouped edge build (scan-free, from R4) ---------------

__global__ __launch_bounds__(256) void zero_kernel(int* __restrict__ p, int n) {
    int i = blockIdx.x * 256 + threadIdx.x;
    if (i < n) p[i] = 0;
}

__global__ __launch_bounds__(256) void degree_kernel(const int* __restrict__ ei,
                                                     int* __restrict__ deg, int E) {
    int e = blockIdx.x * 256 + threadIdx.x;
    if (e < E) atomicAdd(&deg[ei[E + e]], 1);
}

// Wave-parallel segment reservation: 64-lane inclusive shfl-scan of degrees,
// ONE atomicAdd per wave on the global counter. Segment order is arbitrary;
// consumers never rely on cross-node ordering (flat kernel reads dsts[k]).
__global__ __launch_bounds__(256) void reserve_kernel(
    const int* __restrict__ deg, int* __restrict__ cur,
    int* __restrict__ total, int n) {
    int i = blockIdx.x * 256 + threadIdx.x;
    int lane = threadIdx.x & 63;
    int d = (i < n) ? deg[i] : 0;
    int s = d;
#pragma unroll
    for (int k = 1; k < 64; k <<= 1) {
        int v = __shfl_up(s, k);
        if (lane >= k) s += v;
    }
    int wavetotal = __shfl(s, 63);
    int base = 0;
    if (lane == 63) base = atomicAdd(total, wavetotal);
    base = __shfl(base, 63);
    if (i < n) cur[i] = base + (s - d);
}

// Scatter edges into dst-grouped order. Carries (src,dst) packed + a permuted
// copy of ea so both edge passes read everything streamed (R1: gathered ea is
// fatal). Scattered payload: 8B sd + 32B ea per edge.
__global__ __launch_bounds__(256) void scatter_kernel(
    const int* __restrict__ ei, const float* __restrict__ ea,
    int* __restrict__ cur, int2* __restrict__ sd, float* __restrict__ eas,
    int E) {
    int e = blockIdx.x * 256 + threadIdx.x;
    if (e >= E) return;
    int s_ = ei[e];
    int d_ = ei[E + e];
    const float4* av = (const float4*)(ea + (long long)e * F_EDGE);
    float4 a0 = av[0], a1 = av[1];
    int p = atomicAdd(&cur[d_], 1);
    sd[p] = make_int2(s_, d_);
    float4* o = (float4*)(eas + (long long)p * F_EDGE);
    o[0] = a0; o[1] = a1;
}

// ---------------- Per-node precompute (unchanged) ---------------------------
//   Pt[n][j][k]   = sum_i feat[n][i] * We[k][i*H+j]   (stored bf16)
//   q[n][j]       = sum_i feat[n][i] * be[i*H+j]
//   aggseed[n][j] = b[j] + sum_i feat[n][i] * root[i*H+j]
template <int IN, bool RELU, bool INIT>
__global__ __launch_bounds__(256) void prep_kernel(
    const float* __restrict__ feat, const float* __restrict__ We,
    const float* __restrict__ be, const float* __restrict__ root,
    const float* __restrict__ b, unsigned short* __restrict__ Pt,
    float* __restrict__ q, float* __restrict__ aggseed, int n_nodes,
    float* __restrict__ out, const float* __restrict__ blast, int out_n) {
    __shared__ float sW[IN * H * 12];
    int tid = threadIdx.x;
    for (int t = tid; t < IN * H * 12; t += 256) {
        int r = t / 12, m = t - r * 12;   // r = i*H + j
        float v = 0.f;
        if (m < 8) v = We[m * (IN * H) + r];
        else if (m == 8) v = be[r];
        else if (m == 9) v = root[r];
        sW[t] = v;
    }
    if (INIT && blockIdx.x == 0) {
        float bl = blast[0];
        for (int t = tid; t < out_n; t += 256) out[t] = bl;
    }
    __syncthreads();

    int n = blockIdx.x * 32 + (tid >> 3);
    if (n >= n_nodes) return;
    int j = tid & 7;

    float f[IN];
    const float4* fv = (const float4*)(feat + (long long)n * IN);
#pragma unroll
    for (int i4 = 0; i4 < IN / 4; ++i4) {
        float4 v = fv[i4];
        f[i4 * 4 + 0] = v.x; f[i4 * 4 + 1] = v.y;
        f[i4 * 4 + 2] = v.z; f[i4 * 4 + 3] = v.w;
    }
    if (RELU) {
#pragma unroll
        for (int i = 0; i < IN; ++i) f[i] = f[i] > 0.f ? f[i] : 0.f;
    }

    float p[8] = {0.f, 0.f, 0.f, 0.f, 0.f, 0.f, 0.f, 0.f};
    float qq = 0.f, hr = 0.f;
#pragma unroll
    for (int i = 0; i < IN; ++i) {
        const float* row = &sW[(i * 8 + j) * 12];
        float4 w0 = *(const float4*)row;
        float4 w1 = *(const float4*)(row + 4);
        float2 br = *(const float2*)(row + 8);
        float fi = f[i];
        p[0] = fmaf(fi, w0.x, p[0]); p[1] = fmaf(fi, w0.y, p[1]);
        p[2] = fmaf(fi, w0.z, p[2]); p[3] = fmaf(fi, w0.w, p[3]);
        p[4] = fmaf(fi, w1.x, p[4]); p[5] = fmaf(fi, w1.y, p[5]);
        p[6] = fmaf(fi, w1.z, p[6]); p[7] = fmaf(fi, w1.w, p[7]);
        qq = fmaf(fi, br.x, qq);
        hr = fmaf(fi, br.y, hr);
    }
    uint4 pw;
    pw.x = (unsigned)f2bf(p[0]) | ((unsigned)f2bf(p[1]) << 16);
    pw.y = (unsigned)f2bf(p[2]) | ((unsigned)f2bf(p[3]) << 16);
    pw.z = (unsigned)f2bf(p[4]) | ((unsigned)f2bf(p[5]) << 16);
    pw.w = (unsigned)f2bf(p[6]) | ((unsigned)f2bf(p[7]) << 16);
    *(uint4*)(Pt + ((long long)n * H + j) * F_EDGE) = pw;
    q[(long long)n * H + j] = qq;
    aggseed[(long long)n * H + j] = hr + b[j];
}

// ---------------- Flat edge kernel over dst-sorted edges --------------------
// One wave = 8 consecutive sorted edges; lane = es*8 + j (es = edge slot).
// All loads issued upfront (no dynamic loop -> full memory-level parallelism,
// the property R2/R4's per-node loops destroyed).
//   m = q[src][j] + sum_k ea[k]*Pt[src][j][k]
// Sorted order => equal dsts are contiguous across es. 3-step segmented
// shfl_down suffix-sum combines same-dst messages; only run-leader lanes
// issue atomics: ~1.2M atomics/pass instead of 6.4M.
__global__ __launch_bounds__(256) void edge_sorted_kernel(
    const int2* __restrict__ sd, const float* __restrict__ eas,
    const unsigned short* __restrict__ Pt, const float* __restrict__ q,
    float* __restrict__ agg, int E) {
    int waveid = blockIdx.x * 4 + (threadIdx.x >> 6);
    int k0 = waveid * 8;
    if (k0 >= E) return;
    int lane = threadIdx.x & 63;
    int es = lane >> 3, j = lane & 7;

    int k = k0 + es;
    int kk = (k < E) ? k : (E - 1);

    int2 se = sd[kk];
    int src = se.x, dst = se.y;

    const float4* av = (const float4*)(eas + (long long)kk * F_EDGE);
    float4 a0 = av[0], a1 = av[1];
    uint4 pw = *(const uint4*)(Pt + ((long long)src * H + j) * F_EDGE);
    float m = q[(long long)src * H + j];

    m = fmaf(a0.x, bflo(pw.x), m);
    m = fmaf(a0.y, bfhi(pw.x), m);
    m = fmaf(a0.z, bflo(pw.y), m);
    m = fmaf(a0.w, bfhi(pw.y), m);
    m = fmaf(a1.x, bflo(pw.z), m);
    m = fmaf(a1.y, bfhi(pw.z), m);
    m = fmaf(a1.z, bflo(pw.w), m);
    m = fmaf(a1.w, bfhi(pw.w), m);
    if (k >= E) m = 0.f;   // tail lanes duplicate edge E-1 with zero weight

    // segmented suffix-sum over es (dsts sorted => runs are contiguous;
    // dst[es+d]==dst[es] implies everything between is the same run)
#pragma unroll
    for (int d = 1; d < 8; d <<= 1) {
        float mo = __shfl_down(m, d * 8);
        int dso = __shfl_down(dst, d * 8);
        if (es + d < 8 && dso == dst) m += mo;
    }
    int dprev = __shfl_up(dst, 8);
    bool leader = (es == 0) || (dprev != dst);
    if (leader) unsafeAtomicAdd(&agg[(long long)dst * H + j], m);
}

// Pool: per-block LDS bins (batch is sorted -> few hot bins per block),
// then one global atomic per nonzero bin.
__global__ __launch_bounds__(256) void pool_kernel(
    const float* __restrict__ h2pre, const int* __restrict__ batch,
    const float* __restrict__ Wlast, float* __restrict__ out,
    int n_nodes, int n_graphs) {
    __shared__ float bins[512];
    bool use_bins = (n_graphs <= 512);
    if (use_bins) {
        for (int t = threadIdx.x; t < n_graphs; t += 256) bins[t] = 0.f;
        __syncthreads();
    }
    float wl[8];
#pragma unroll
    for (int j = 0; j < 8; ++j) wl[j] = Wlast[j];

    int base = blockIdx.x * 1024;
#pragma unroll
    for (int r = 0; r < 4; ++r) {
        int n = base + r * 256 + threadIdx.x;
        if (n < n_nodes) {
            const float4* hv = (const float4*)(h2pre + (long long)n * H);
            float4 h0 = hv[0], h1 = hv[1];
            float c = 0.f;
            c = fmaf(fmaxf(h0.x, 0.f), wl[0], c);
            c = fmaf(fmaxf(h0.y, 0.f), wl[1], c);
            c = fmaf(fmaxf(h0.z, 0.f), wl[2], c);
            c = fmaf(fmaxf(h0.w, 0.f), wl[3], c);
            c = fmaf(fmaxf(h1.x, 0.f), wl[4], c);
            c = fmaf(fmaxf(h1.y, 0.f), wl[5], c);
            c = fmaf(fmaxf(h1.z, 0.f), wl[6], c);
            c = fmaf(fmaxf(h1.w, 0.f), wl[7], c);
            if (use_bins) atomicAdd(&bins[batch[n]], c);
            else unsafeAtomicAdd(&out[batch[n]], c);
        }
    }
    if (use_bins) {
        __syncthreads();
        for (int t = threadIdx.x; t < n_graphs; t += 256) {
            float v = bins[t];
            if (v != 0.f) unsafeAtomicAdd(&out[t], v);
        }
    }
}

extern "C" void kernel_launch(void* const* d_in, const int* in_sizes, int n_in,
                              void* d_out, int out_size, void* d_ws, size_t ws_size,
                              hipStream_t stream) {
    const float* x     = (const float*)d_in[0];
    const int*   ei    = (const int*)d_in[1];
    const float* ea    = (const float*)d_in[2];
    const int*   batch = (const int*)d_in[3];
    const float* We1   = (const float*)d_in[4];
    const float* be1   = (const float*)d_in[5];
    const float* root1 = (const float*)d_in[6];
    const float* b1    = (const float*)d_in[7];
    const float* We2   = (const float*)d_in[8];
    const float* be2   = (const float*)d_in[9];
    const float* root2 = (const float*)d_in[10];
    const float* b2    = (const float*)d_in[11];
    const float* Wlast = (const float*)d_in[12];
    const float* blast = (const float*)d_in[13];
    float* out = (float*)d_out;

    int F_IN_rt = 16;
    int n_nodes = in_sizes[0] / F_IN_rt;
    int E = in_sizes[1] / 2;

    char* w = (char*)d_ws;
    auto take = [&](size_t bytes) {
        char* p = w;
        w += (bytes + 15) & ~(size_t)15;
        return p;
    };
    unsigned short* Pt1 = (unsigned short*)take((size_t)n_nodes * H * F_EDGE * 2);
    unsigned short* Pt2 = (unsigned short*)take((size_t)n_nodes * H * F_EDGE * 2);
    float* q1    = (float*)take((size_t)n_nodes * H * 4);
    float* q2    = (float*)take((size_t)n_nodes * H * 4);
    float* h1    = (float*)take((size_t)n_nodes * H * 4);   // seed1 -> h1 in place
    float* h2    = (float*)take((size_t)n_nodes * H * 4);   // seed2 -> h2 in place
    int* deg     = (int*)take((size_t)(n_nodes + 1) * 4);   // deg[n_nodes] = total ctr
    int* cur     = (int*)take((size_t)n_nodes * 4);
    int2* sd     = (int2*)take((size_t)E * 8);
    float* eas   = (float*)take((size_t)E * F_EDGE * 4);

    int* total = deg + n_nodes;

    int nbz = (n_nodes + 1 + 255) / 256;
    int nbn = (n_nodes + 255) / 256;
    int nbe = (E + 255) / 256;

    // dst-grouped build (scan-free)
    zero_kernel<<<nbz, 256, 0, stream>>>(deg, n_nodes + 1);
    degree_kernel<<<nbe, 256, 0, stream>>>(ei, deg, E);
    reserve_kernel<<<nbn, 256, 0, stream>>>(deg, cur, total, n_nodes);
    scatter_kernel<<<nbe, 256, 0, stream>>>(ei, ea, cur, sd, eas, E);

    int nblocks = (n_nodes + 31) / 32;
    prep_kernel<16, false, true><<<nblocks, 256, 0, stream>>>(
        x, We1, be1, root1, b1, Pt1, q1, h1, n_nodes, out, blast, out_size);

    int eblks = (E + 31) / 32;   // 8 edges/wave, 4 waves/block
    edge_sorted_kernel<<<eblks, 256, 0, stream>>>(sd, eas, Pt1, q1, h1, E);

    prep_kernel<H, true, false><<<nblocks, 256, 0, stream>>>(
        h1, We2, be2, root2, b2, Pt2, q2, h2, n_nodes, nullptr, nullptr, 0);

    edge_sorted_kernel<<<eblks, 256, 0, stream>>>(sd, eas, Pt2, q2, h2, E);

    int pblocks = (n_nodes + 1023) / 1024;
    pool_kernel<<<pblocks, 256, 0, stream>>>(h2, batch, Wlast, out, n_nodes, out_size);
}